// Round 14
// baseline (81.507 us; speedup 1.0000x reference)
//
#include <hip/hip_runtime.h>

// Chamfer distance, B=16, N=M=4096, 2-D fp32 points, prefix-length masks.
// d_out: [fwd 16*4096][bwd 16*4096] fp32.
//
// R20 = R14/R18 skeleton, 256-pt chunks (one variable: chunk size).
//  - R19 (flatten critical path) null -> scan is WORK-bound: 14.4us
//    (R16 REP-instrumented) at ~4x-below-peak burst clock (DVFS,
//    uncontrollable; consistent across all 13 rounds). Scan instr count
//    is already at the fp32 floor (1.5 VALU/point-query; MFMA-bf16/f16
//    fails cancellation: d2 needs ~1e-3 abs precision from ~2-magnitude
//    terms). Scan is irreducible short of a spatial-grid rewrite.
//  - Target: R16's non-scan 15.6us (staging, Q-loads, lookup, atomics,
//    prologue/drain) -- all per-block costs. R18 cleared atomics as the
//    dominant term (conditional skip null). Halve BLOCK COUNT: 256-pt
//    chunks, same 256-thread shape (R17 changed threads too; not here).
//    Per query-slice: staging barriers, Q-loads, atomic fan-in (32->16)
//    all halve. Scan total unchanged by construction.
//  - qg split at 8 slices keeps per-block KA <= 8 (VGPR ~60, 2 blocks/CU
//    under launch_bounds(256,2)); nqg in {1,2}.
//  - Grid 1024 = worst case 32 rows x 16 chunks x 2 qg exactly; spare
//    blocks (present iff some row has Lp==0, freeing 32 units each)
//    sentinel those rows. All R14/R18 machinery carried: 0x7F memset init
//    (out_size = ELEMENT count -> x4 bytes), atomic-only writes (min
//    commutes with sqrt, nonneg f32 bits uint-monotone), pc0&qg0
//    tail-zero atomicMin(0), stale-safe conditional atomicMin, exact-KA
//    templates, 2 v_pk_fma_f32 + v_min3_f32 per pair per query, full f32
//    (absmax ~2e-3), no fences.
//  - Pre-committed read: <=75 confirmed (R21: 512-pt chunks); >=77 null
//    -> non-scan is launch/drain overhead -> write the roofline case
//    (fill 40 + fixed ~9 + work-bound main ~28 ~= 78; levers exhausted).

typedef float f2 __attribute__((ext_vector_type(2)));

template<int KA>
__device__ __forceinline__ void scan_queries(
    const float* __restrict__ Qrow,          // row base of query cloud
    const float4* __restrict__ sxy, const f2* __restrict__ sn,
    unsigned* __restrict__ orow_u, int tid, int q0)  // q0 = qg*2048
{
    // KA queries per thread (q0 + tid + k*256); 4 state VGPRs per query.
    float mx[KA], my[KA], s2[KA], best[KA];
    #pragma unroll
    for (int k = 0; k < KA; ++k) {
        const float2 q = ((const float2*)Qrow)[q0 + tid + k * 256];
        mx[k] = -2.f * q.x;
        my[k] = -2.f * q.y;
        s2[k] = fmaf(q.x, q.x, q.y * q.y);
        best[k] = 3.0e38f;
    }

    // Per point-pair per query: 2 v_pk_fma_f32 (scalar op_sel broadcast)
    // + 1 v_min3_f32; 2 broadcast LDS reads amortized over KA queries.
    #pragma unroll 4
    for (int j = 0; j < 128; ++j) {
        const float4 xy = sxy[j];
        const f2 xp = f2{xy.x, xy.y};
        const f2 yp = f2{xy.z, xy.w};
        const f2 np = sn[j];
        #pragma unroll
        for (int k = 0; k < KA; ++k) {
            f2 v = xp * mx[k] + np;       // pk_fma: n - 2qx*tx
            v = yp * my[k] + v;           // pk_fma: n - 2q.t
            best[k] = fminf(best[k], fminf(v.x, v.y));  // v_min3_f32
        }
    }

    // Stale-safe conditional atomicMin (R18): values only decrease, so a
    // stale read >= current; candidate >= stale => RMW cannot improve.
    unsigned cur[KA];
    #pragma unroll
    for (int k = 0; k < KA; ++k)
        cur[k] = orow_u[q0 + tid + k * 256];
    #pragma unroll
    for (int k = 0; k < KA; ++k) {
        const float d = sqrtf(fmaxf(best[k] + s2[k], 0.f));
        const unsigned bits = __float_as_uint(d);
        if (bits < cur[k])
            atomicMin(orow_u + q0 + tid + k * 256, bits);
    }
}

__global__ __launch_bounds__(256, 2) void chamfer_main(
    const float* __restrict__ src, const float* __restrict__ tgt,
    const int* __restrict__ slen, const int* __restrict__ tlen,
    float* __restrict__ out)
{
    __shared__ float4 sh_xy[128];  // {x0,x1,y0,y1} per point-pair
    __shared__ f2     sh_n[128];   // {|t0|^2, |t1|^2}

    const int g   = blockIdx.x;
    const int tid = threadIdx.x;

    // Compacted lookup: g -> (row, pc, qg). Uniform SALU.
    int row = -1, u = 0, nqg_s = 1, Lp = 0, Lq = 0, acc = 0;
    #pragma unroll
    for (int rr = 0; rr < 32; ++rr) {
        const int Ls  = (rr < 16) ? tlen[rr] : slen[rr - 16];  // search len
        const int Lqq = (rr < 16) ? slen[rr] : tlen[rr - 16];  // query len
        const int nch  = (Ls + 255) >> 8;                      // 256-pt chunks
        const int kact = (Lqq + 255) >> 8;                     // 256-q slices
        const int nqg  = (kact > 8) ? 2 : 1;                   // 8-slice groups
        const int units = nch * nqg;                           // 0 iff Ls==0
        if (row < 0 && g < acc + units) {
            row = rr; u = g - acc; nqg_s = nqg; Lp = Ls; Lq = Lqq;
        }
        acc += units;
    }

    if (row < 0) {
        // Spare block: rows with NO compute units (Lp == 0): min over
        // empty set = BIG -> sqrt(1e10) for q < Lq, 0 beyond. Atomic-only.
        const int cr = g - acc;                  // acc == total active units
        if (cr < 32) {
            const int dirc = cr >> 4, bc = cr & 15;
            const int Lpc = dirc ? slen[bc] : tlen[bc];
            if (Lpc == 0) {
                const int Lqc = dirc ? tlen[bc] : slen[bc];
                unsigned* op = (unsigned*)(out + cr * 4096);
                const unsigned sent = __float_as_uint(sqrtf(1e10f));
                #pragma unroll
                for (int k = 0; k < 16; ++k) {
                    const int q = tid + k * 256;
                    atomicMin(op + q, (q < Lqc) ? sent : 0u);
                }
            }
        }
        return;
    }
    // Unit -> (pc, qg); nqg_s in {1,2} so shift/mask, no divide.
    const int pc = (nqg_s == 2) ? (u >> 1) : u;
    const int qg = (nqg_s == 2) ? (u & 1) : 0;
    const int dir = row >> 4, b = row & 15;
    unsigned* orow_u = (unsigned*)(out + row * 4096);

    // One block per row (pc==0, qg==0) forces the padded-query tail to 0
    // via atomicMin(0): order-independent vs dead-value atomics. Covers
    // the whole row when Lq == 0.
    if (pc == 0 && qg == 0) {
        #pragma unroll
        for (int k = 0; k < 16; ++k) {
            const int q = tid + k * 256;
            if (q >= Lq) atomicMin(orow_u + q, 0u);
        }
    }

    const int KACT = (Lq + 255) >> 8;
    const int KB = min(8, KACT - qg * 8);        // this block's slices
    if (KB <= 0) return;                         // Lq==0 row (tail done)

    const float* Q = dir ? tgt : src;
    const float* P = dir ? src : tgt;

    // Stage 256 points (128 pairs), pair-packed; poison n for idx >= Lp.
    if (tid < 128) {
        const int base = pc * 256 + tid * 2;
        const float4 pp = ((const float4*)P)[(b * 4096 + base) >> 1];  // {x0,y0,x1,y1}
        const float n0 = (base + 0 < Lp) ? fmaf(pp.x, pp.x, pp.y * pp.y) : 1e30f;
        const float n1 = (base + 1 < Lp) ? fmaf(pp.z, pp.z, pp.w * pp.w) : 1e30f;
        sh_xy[tid] = make_float4(pp.x, pp.z, pp.y, pp.w);    // {x0,x1,y0,y1}
        sh_n[tid]  = f2{n0, n1};
    }
    __syncthreads();

    const float* Qrow = Q + b * 8192;            // row base (float2 elems)
    const int q0 = qg * 2048;                    // first query of this group

    switch (KB) {                                // exact slice count 1..8
        case 1:  scan_queries<1>(Qrow, sh_xy, sh_n, orow_u, tid, q0); break;
        case 2:  scan_queries<2>(Qrow, sh_xy, sh_n, orow_u, tid, q0); break;
        case 3:  scan_queries<3>(Qrow, sh_xy, sh_n, orow_u, tid, q0); break;
        case 4:  scan_queries<4>(Qrow, sh_xy, sh_n, orow_u, tid, q0); break;
        case 5:  scan_queries<5>(Qrow, sh_xy, sh_n, orow_u, tid, q0); break;
        case 6:  scan_queries<6>(Qrow, sh_xy, sh_n, orow_u, tid, q0); break;
        case 7:  scan_queries<7>(Qrow, sh_xy, sh_n, orow_u, tid, q0); break;
        default: scan_queries<8>(Qrow, sh_xy, sh_n, orow_u, tid, q0); break;
    }
}

extern "C" void kernel_launch(void* const* d_in, const int* in_sizes, int n_in,
                              void* d_out, int out_size, void* d_ws, size_t ws_size,
                              hipStream_t stream) {
    const float* src = (const float*)d_in[0];   // [16,4096,2] f32
    const float* tgt = (const float*)d_in[1];   // [16,4096,2] f32
    const int* slen  = (const int*)d_in[2];     // [16] i32
    const int* tlen  = (const int*)d_in[3];     // [16] i32
    (void)d_ws; (void)ws_size;                  // workspace unused

    // Init out to 0x7F7F7F7F = 3.39e38f (> any candidate). out_size is the
    // ELEMENT count -> bytes = x4. 131072 elems -> 524288 bytes.
    hipMemsetAsync(d_out, 0x7F, (size_t)out_size * sizeof(float), stream);
    // Worst-case units = 32 rows x 16 chunks x 2 qgroups = 1024.
    chamfer_main<<<1024, 256, 0, stream>>>(src, tgt, slen, tlen, (float*)d_out);
}

// Round 15
// 77.916 us; speedup vs baseline: 1.0461x; 1.0461x over previous
//
#include <hip/hip_runtime.h>

// Chamfer distance, B=16, N=M=4096, 2-D fp32 points, prefix-length masks.
// d_out: [fwd 16*4096][bwd 16*4096] fp32.
//
// R21 = TERMINAL REVERT to R19 (measured best, 78.4us).
//  - R20 (256-pt chunks, half the blocks) hit its pre-committed null
//    (81.5 >= 77): per-block overhead is not the remaining term.
//  - Complete lever inventory, all measured null or negative: work cuts
//    (R9 45%, R18 exact-KACT), balance (R19), block count (R20), atomic
//    fan-in/conditional (R13/R18), dispatch count (R12-R14, +3.6 total),
//    structural rewrites (R7/R8/R15/R17: -6..-16 each).
//  - Floor accounting (measured): fill 40.5 (harness ws-poison @83% HBM,
//    its own roofline) + fixed launch/graph ~20 (R11 A/B: +19.7us per
//    extra dispatch) + main ~17, of which scan = 14.4 (R16 REP=4) is
//    WORK-bound (R19 balance-null) at burst-DVFS clock, already at
//    1.5 fp32-VALU/point-query (no MFMA: d2 cancellation needs ~1e-3 abs
//    from ~2-magnitude terms). Remaining lever (spatial grid, ~-8us EV)
//    is below the measured cost of structural rewrites in this regime.
//  - This file is R19 verbatim: query-split blocks (KA<=4), compacted
//    (row, pc, qg) lookup, launch_bounds(256,4), 0x7F memset init
//    (out_size is ELEMENT count -> x4 bytes), atomic-only out writes
//    (min commutes with sqrt; nonneg f32 bits uint-monotone), pc0&qg0
//    tail-zero atomicMin(0), spare-block sentinels for Lp==0 rows,
//    stale-safe conditional atomicMin, 2 v_pk_fma_f32 + v_min3_f32 per
//    pair per query, full f32 (absmax ~2e-3), no fences (R3 lesson).

typedef float f2 __attribute__((ext_vector_type(2)));

template<int KA>
__device__ __forceinline__ void scan_queries(
    const float* __restrict__ Qrow,          // row base of query cloud
    const float4* __restrict__ sxy, const f2* __restrict__ sn,
    unsigned* __restrict__ orow_u, int tid, int q0)  // q0 = qg*1024
{
    // KA queries per thread (q0 + tid + k*256); 4 state VGPRs per query.
    float mx[KA], my[KA], s2[KA], best[KA];
    #pragma unroll
    for (int k = 0; k < KA; ++k) {
        const float2 q = ((const float2*)Qrow)[q0 + tid + k * 256];
        mx[k] = -2.f * q.x;
        my[k] = -2.f * q.y;
        s2[k] = fmaf(q.x, q.x, q.y * q.y);
        best[k] = 3.0e38f;
    }

    // Per point-pair per query: 2 v_pk_fma_f32 (scalar op_sel broadcast)
    // + 1 v_min3_f32; 2 broadcast LDS reads amortized over KA queries.
    #pragma unroll 4
    for (int j = 0; j < 64; ++j) {
        const float4 xy = sxy[j];
        const f2 xp = f2{xy.x, xy.y};
        const f2 yp = f2{xy.z, xy.w};
        const f2 np = sn[j];
        #pragma unroll
        for (int k = 0; k < KA; ++k) {
            f2 v = xp * mx[k] + np;       // pk_fma: n - 2qx*tx
            v = yp * my[k] + v;           // pk_fma: n - 2q.t
            best[k] = fminf(best[k], fminf(v.x, v.y));  // v_min3_f32
        }
    }

    // Stale-safe conditional atomicMin (R18): values only decrease, so a
    // stale read >= current; candidate >= stale => RMW cannot improve.
    unsigned cur[KA];
    #pragma unroll
    for (int k = 0; k < KA; ++k)
        cur[k] = orow_u[q0 + tid + k * 256];
    #pragma unroll
    for (int k = 0; k < KA; ++k) {
        const float d = sqrtf(fmaxf(best[k] + s2[k], 0.f));
        const unsigned bits = __float_as_uint(d);
        if (bits < cur[k])
            atomicMin(orow_u + q0 + tid + k * 256, bits);
    }
}

__global__ __launch_bounds__(256, 4) void chamfer_main(
    const float* __restrict__ src, const float* __restrict__ tgt,
    const int* __restrict__ slen, const int* __restrict__ tlen,
    float* __restrict__ out)
{
    __shared__ float4 sh_xy[64];   // {x0,x1,y0,y1} per point-pair
    __shared__ f2     sh_n[64];    // {|t0|^2, |t1|^2}

    const int g   = blockIdx.x;
    const int tid = threadIdx.x;

    // Compacted lookup: g -> (row, pc, qg). Uniform SALU.
    int row = -1, pc = 0, qg = 0, Lp = 0, Lq = 0, acc = 0;
    #pragma unroll
    for (int rr = 0; rr < 32; ++rr) {
        const int Ls  = (rr < 16) ? tlen[rr] : slen[rr - 16];  // search len
        const int Lqq = (rr < 16) ? slen[rr] : tlen[rr - 16];  // query len
        const int nch  = (Ls + 127) >> 7;                      // 128-pt chunks
        const int kact = (Lqq + 255) >> 8;                     // 256-q slices
        int nqg = (kact + 3) >> 2;                             // 4-slice groups
        if (nqg == 0) nqg = 1;                                 // keep pc0/qg0
        const int units = nch * nqg;                           // 0 iff Ls==0
        if (row < 0 && g < acc + units) {
            row = rr; const int u = g - acc;
            pc = u / nqg; qg = u - pc * nqg;                   // pc-major
            Lp = Ls; Lq = Lqq;
        }
        acc += units;
    }

    if (row < 0) {
        // Spare block: rows with NO compute units (Lp == 0): min over
        // empty set = BIG -> sqrt(1e10) for q < Lq, 0 beyond. Atomic-only.
        const int cr = g - acc;                  // acc == total active units
        if (cr < 32) {
            const int dirc = cr >> 4, bc = cr & 15;
            const int Lpc = dirc ? slen[bc] : tlen[bc];
            if (Lpc == 0) {
                const int Lqc = dirc ? tlen[bc] : slen[bc];
                unsigned* op = (unsigned*)(out + cr * 4096);
                const unsigned sent = __float_as_uint(sqrtf(1e10f));
                #pragma unroll
                for (int k = 0; k < 16; ++k) {
                    const int q = tid + k * 256;
                    atomicMin(op + q, (q < Lqc) ? sent : 0u);
                }
            }
        }
        return;
    }
    const int dir = row >> 4, b = row & 15;
    unsigned* orow_u = (unsigned*)(out + row * 4096);

    // One block per row (pc==0, qg==0) forces the padded-query tail to 0
    // via atomicMin(0): order-independent vs dead-value atomics. Covers
    // the whole row when Lq == 0.
    if (pc == 0 && qg == 0) {
        #pragma unroll
        for (int k = 0; k < 16; ++k) {
            const int q = tid + k * 256;
            if (q >= Lq) atomicMin(orow_u + q, 0u);
        }
    }

    const int KACT = (Lq + 255) >> 8;
    const int KB = min(4, KACT - qg * 4);        // this block's slices
    if (KB <= 0) return;                         // Lq==0 row (tail done)

    const float* Q = dir ? tgt : src;
    const float* P = dir ? src : tgt;

    // Stage 128 points (64 pairs), pair-packed; poison n for idx >= Lp.
    if (tid < 64) {
        const int base = pc * 128 + tid * 2;
        const float4 pp = ((const float4*)P)[(b * 4096 + base) >> 1];  // {x0,y0,x1,y1}
        const float n0 = (base + 0 < Lp) ? fmaf(pp.x, pp.x, pp.y * pp.y) : 1e30f;
        const float n1 = (base + 1 < Lp) ? fmaf(pp.z, pp.z, pp.w * pp.w) : 1e30f;
        sh_xy[tid] = make_float4(pp.x, pp.z, pp.y, pp.w);    // {x0,x1,y0,y1}
        sh_n[tid]  = f2{n0, n1};
    }
    __syncthreads();

    const float* Qrow = Q + b * 8192;            // row base (float2 elems)
    const int q0 = qg * 1024;                    // first query of this group

    switch (KB) {                                // exact slice count 1..4
        case 1:  scan_queries<1>(Qrow, sh_xy, sh_n, orow_u, tid, q0); break;
        case 2:  scan_queries<2>(Qrow, sh_xy, sh_n, orow_u, tid, q0); break;
        case 3:  scan_queries<3>(Qrow, sh_xy, sh_n, orow_u, tid, q0); break;
        default: scan_queries<4>(Qrow, sh_xy, sh_n, orow_u, tid, q0); break;
    }
}

extern "C" void kernel_launch(void* const* d_in, const int* in_sizes, int n_in,
                              void* d_out, int out_size, void* d_ws, size_t ws_size,
                              hipStream_t stream) {
    const float* src = (const float*)d_in[0];   // [16,4096,2] f32
    const float* tgt = (const float*)d_in[1];   // [16,4096,2] f32
    const int* slen  = (const int*)d_in[2];     // [16] i32
    const int* tlen  = (const int*)d_in[3];     // [16] i32
    (void)d_ws; (void)ws_size;                  // workspace unused

    // Init out to 0x7F7F7F7F = 3.39e38f (> any candidate). out_size is the
    // ELEMENT count -> bytes = x4. 131072 elems -> 524288 bytes.
    hipMemsetAsync(d_out, 0x7F, (size_t)out_size * sizeof(float), stream);
    // Worst-case units = 32 rows x 32 chunks x 4 qgroups = 4096.
    chamfer_main<<<4096, 256, 0, stream>>>(src, tgt, slen, tlen, (float*)d_out);
}